// Round 1
// baseline (489.893 us; speedup 1.0000x reference)
//
#include <hip/hip_runtime.h>
#include <hip/hip_bf16.h>
#include <stdint.h>

#define Bn 8
#define Ln 1024
#define Dn 1024
#define Hn 16
#define HDn 64
#define Mn (Bn*Ln)   // 8192
#define Kn 1024

typedef __attribute__((ext_vector_type(8))) __bf16 bf16x8;
typedef __attribute__((ext_vector_type(4))) float f32x4;

__device__ __forceinline__ unsigned short f2bf(float f) {
    unsigned int u = __float_as_uint(f);
    unsigned int r = (u + 0x7fff + ((u >> 16) & 1)) >> 16;
    return (unsigned short)r;
}

__device__ __forceinline__ void gload_lds16(void* lds, const void* g) {
    __builtin_amdgcn_global_load_lds(
        (const __attribute__((address_space(1))) unsigned int*)g,
        (__attribute__((address_space(3))) unsigned int*)lds,
        16, 0, 0);
}

// ---------------- fp32 -> bf16 elementwise convert ----------------
__global__ void cvt_bf16_kernel(const float* __restrict__ in,
                                unsigned short* __restrict__ out) {
    size_t i = ((size_t)blockIdx.x * blockDim.x + threadIdx.x) * 4;
    float4 f = *(const float4*)(in + i);
    ushort4 o;
    o.x = f2bf(f.x); o.y = f2bf(f.y); o.z = f2bf(f.z); o.w = f2bf(f.w);
    *(ushort4*)(out + i) = o;
}

// ---------------- W [K][N] fp32 -> W^T [N][K] bf16 ----------------
__global__ void transpose_w_kernel(const float* __restrict__ W,
                                   unsigned short* __restrict__ Wt) {
    __shared__ float tile[32][33];
    int bx = blockIdx.x;          // N tile
    int by = blockIdx.y;          // K tile
    int tx = threadIdx.x;         // 0..31
    int ty = threadIdx.y;         // 0..7
    int col = bx * 32 + tx;
    for (int i = 0; i < 32; i += 8)
        tile[ty + i][tx] = W[(size_t)(by * 32 + ty + i) * Dn + col];
    __syncthreads();
    int ok = by * 32 + tx;        // k index (contiguous in Wt)
    for (int i = 0; i < 32; i += 8)
        Wt[(size_t)(bx * 32 + ty + i) * Kn + ok] = f2bf(tile[tx][ty + i]);
}

// ---------------- bf16 GEMM: C = A[M,K] * Bt[N,K]^T + bias --------
// mode 0: dst[((b*H+h)*L + l)*HD + hd]   (q/k/q2/k2 layout)
// mode 1: dst[((b*H+h)*HD + hd)*L + l]   (V^T layout)
__launch_bounds__(256, 2)
__global__ void gemm_proj_kernel(const unsigned short* __restrict__ Abf,
                                 const unsigned short* __restrict__ Bt,
                                 const float* __restrict__ bias,
                                 unsigned short* __restrict__ dst,
                                 int mode) {
    __shared__ __align__(16) unsigned short As[128 * 32];
    __shared__ __align__(16) unsigned short Bs[128 * 32];
    int m0 = blockIdx.y * 128;
    int n0 = blockIdx.x * 128;
    int t = threadIdx.x;
    int lane = t & 63, wave = t >> 6;
    int wm = (wave >> 1) * 64, wn = (wave & 1) * 64;
    int lrow = lane & 15, lquad = lane >> 4;

    f32x4 acc[4][4] = {};
    int arow = t >> 2;            // 0..63
    int acol = (t & 3) * 8;       // element offset within 32-col row

    for (int k0 = 0; k0 < Kn; k0 += 32) {
        gload_lds16(&As[t * 8],         Abf + (size_t)(m0 + arow) * Kn + k0 + acol);
        gload_lds16(&As[(t + 256) * 8], Abf + (size_t)(m0 + 64 + arow) * Kn + k0 + acol);
        gload_lds16(&Bs[t * 8],         Bt  + (size_t)(n0 + arow) * Kn + k0 + acol);
        gload_lds16(&Bs[(t + 256) * 8], Bt  + (size_t)(n0 + 64 + arow) * Kn + k0 + acol);
        __syncthreads();
        bf16x8 af[4], bfr[4];
        for (int i = 0; i < 4; i++)
            af[i] = *(const bf16x8*)&As[(wm + i * 16 + lrow) * 32 + lquad * 8];
        for (int j = 0; j < 4; j++)
            bfr[j] = *(const bf16x8*)&Bs[(wn + j * 16 + lrow) * 32 + lquad * 8];
        for (int i = 0; i < 4; i++)
            for (int j = 0; j < 4; j++)
                acc[i][j] = __builtin_amdgcn_mfma_f32_16x16x32_bf16(af[i], bfr[j], acc[i][j], 0, 0, 0);
        __syncthreads();
    }

    for (int j = 0; j < 4; j++) {
        int gn = n0 + wn + j * 16 + lrow;
        float bv = bias[gn];
        int h = gn >> 6, hd = gn & 63;
        for (int i = 0; i < 4; i++) {
            for (int r = 0; r < 4; r++) {
                int gm = m0 + wm + i * 16 + lquad * 4 + r;   // C row = quad*4+reg
                int b = gm >> 10, ll = gm & 1023;
                unsigned short v = f2bf(acc[i][j][r] + bv);
                if (mode == 0)
                    dst[((size_t)(b * Hn + h) * Ln + ll) * HDn + hd] = v;
                else
                    dst[((size_t)(b * Hn + h) * HDn + hd) * Ln + ll] = v;
            }
        }
    }
}

// ---------------- flash attention over 2 score terms --------------
__launch_bounds__(256, 2)
__global__ void attn_kernel(const unsigned short* __restrict__ qb,
                            const unsigned short* __restrict__ kb,
                            const unsigned short* __restrict__ q2b,
                            const unsigned short* __restrict__ k2b,
                            const unsigned short* __restrict__ vtb,
                            const float* __restrict__ mask,
                            float* __restrict__ out) {
    __shared__ __align__(16) unsigned short Ks[64 * 64];
    __shared__ __align__(16) unsigned short K2s[64 * 64];
    __shared__ __align__(16) unsigned short VTs[64 * 64];
    __shared__ __align__(16) unsigned short Ps[4 * 16 * 64];

    int bh = blockIdx.y;                 // 0..127
    int qt = blockIdx.x;                 // 0..15
    int b = bh >> 4, h = bh & 15;
    int t = threadIdx.x;
    int lane = t & 63, wave = t >> 6;
    int lrow = lane & 15, lquad = lane >> 4;
    int qbase = qt * 64 + wave * 16;

    // Q / Q2 A-fragments (A[m=lane&15][k=quad*8+j], two k-steps of 32)
    bf16x8 qf[2], q2f[2];
    for (int kk = 0; kk < 2; kk++) {
        size_t off = ((size_t)bh * Ln + qbase + lrow) * HDn + kk * 32 + lquad * 8;
        qf[kk]  = *(const bf16x8*)(qb + off);
        q2f[kk] = *(const bf16x8*)(q2b + off);
    }

    f32x4 O[4] = {};
    float mrow[4] = {-1e30f, -1e30f, -1e30f, -1e30f};
    float lsum[4] = {};

    int srow = t >> 3;                   // 0..31 (64 cols * 2B = 8 chunks/row)
    int scol = (t & 7) * 8;
    const float* maskb = mask + (size_t)b * Ln;

    for (int kt = 0; kt < 16; kt++) {
        int key0 = kt * 64;
        gload_lds16(&Ks[t * 8],          kb  + ((size_t)bh * Ln + key0 + srow) * HDn + scol);
        gload_lds16(&Ks[(t + 256) * 8],  kb  + ((size_t)bh * Ln + key0 + 32 + srow) * HDn + scol);
        gload_lds16(&K2s[t * 8],         k2b + ((size_t)bh * Ln + key0 + srow) * HDn + scol);
        gload_lds16(&K2s[(t + 256) * 8], k2b + ((size_t)bh * Ln + key0 + 32 + srow) * HDn + scol);
        gload_lds16(&VTs[t * 8],         vtb + ((size_t)bh * HDn + srow) * Ln + key0 + scol);
        gload_lds16(&VTs[(t + 256) * 8], vtb + ((size_t)bh * HDn + 32 + srow) * Ln + key0 + scol);
        __syncthreads();

        // S = (Q K^T + Q2 K2^T)
        f32x4 S[4] = {};
        for (int kk = 0; kk < 2; kk++) {
            for (int j = 0; j < 4; j++) {
                bf16x8 kf = *(const bf16x8*)&Ks[(j * 16 + lrow) * 64 + kk * 32 + lquad * 8];
                S[j] = __builtin_amdgcn_mfma_f32_16x16x32_bf16(qf[kk], kf, S[j], 0, 0, 0);
            }
            for (int j = 0; j < 4; j++) {
                bf16x8 kf = *(const bf16x8*)&K2s[(j * 16 + lrow) * 64 + kk * 32 + lquad * 8];
                S[j] = __builtin_amdgcn_mfma_f32_16x16x32_bf16(q2f[kk], kf, S[j], 0, 0, 0);
            }
        }
        float mk[4];
        for (int j = 0; j < 4; j++) mk[j] = maskb[key0 + j * 16 + lrow];
        for (int j = 0; j < 4; j++)
            for (int r = 0; r < 4; r++)
                S[j][r] = S[j][r] * 0.125f + mk[j];

        // online softmax (rows live on (quad, reg); reduce over lane bits 0..3)
        float newm[4], alpha[4];
        for (int r = 0; r < 4; r++) {
            float mx = fmaxf(fmaxf(S[0][r], S[1][r]), fmaxf(S[2][r], S[3][r]));
            for (int d = 1; d < 16; d <<= 1)
                mx = fmaxf(mx, __shfl_xor(mx, d, 64));
            newm[r] = fmaxf(mrow[r], mx);
            alpha[r] = __expf(mrow[r] - newm[r]);
            mrow[r] = newm[r];
        }
        for (int j = 0; j < 4; j++)
            for (int r = 0; r < 4; r++)
                S[j][r] = __expf(S[j][r] - newm[r]);
        for (int r = 0; r < 4; r++) {
            float s = S[0][r] + S[1][r] + S[2][r] + S[3][r];
            for (int d = 1; d < 16; d <<= 1)
                s += __shfl_xor(s, d, 64);
            lsum[r] = lsum[r] * alpha[r] + s;
        }
        for (int j = 0; j < 4; j++)
            for (int r = 0; r < 4; r++)
                O[j][r] *= alpha[r];

        // P: C-layout -> LDS -> A-operand layout
        unsigned short* pw = &Ps[wave * 16 * 64];
        for (int j = 0; j < 4; j++)
            for (int r = 0; r < 4; r++)
                pw[(lquad * 4 + r) * 64 + j * 16 + lrow] = f2bf(S[j][r]);
        __syncthreads();

        for (int kk = 0; kk < 2; kk++) {
            bf16x8 pf = *(const bf16x8*)&pw[lrow * 64 + kk * 32 + lquad * 8];
            for (int j = 0; j < 4; j++) {
                bf16x8 vf = *(const bf16x8*)&VTs[(j * 16 + lrow) * 64 + kk * 32 + lquad * 8];
                O[j] = __builtin_amdgcn_mfma_f32_16x16x32_bf16(pf, vf, O[j], 0, 0, 0);
            }
        }
        __syncthreads();
    }

    for (int j = 0; j < 4; j++) {
        for (int r = 0; r < 4; r++) {
            int ql = qbase + lquad * 4 + r;
            out[((size_t)b * Ln + ql) * Dn + h * HDn + j * 16 + lrow] = O[j][r] / lsum[r];
        }
    }
}

extern "C" void kernel_launch(void* const* d_in, const int* in_sizes, int n_in,
                              void* d_out, int out_size, void* d_ws, size_t ws_size,
                              hipStream_t stream) {
    const float* hidden = (const float*)d_in[0];
    const float* mask   = (const float*)d_in[1];
    const float* source = (const float*)d_in[2];
    const float* Wq  = (const float*)d_in[3];
    const float* bq  = (const float*)d_in[4];
    const float* Wk  = (const float*)d_in[5];
    const float* bk  = (const float*)d_in[6];
    const float* Wv  = (const float*)d_in[7];
    const float* bv  = (const float*)d_in[8];
    const float* Wq2 = (const float*)d_in[9];
    const float* bq2 = (const float*)d_in[10];
    const float* Wk2 = (const float*)d_in[11];
    const float* bk2 = (const float*)d_in[12];
    float* out = (float*)d_out;

    char* ws = (char*)d_ws;
    const size_t act_sz = (size_t)Mn * Dn * 2;   // 16 MB
    const size_t w_sz   = (size_t)Kn * Dn * 2;   // 2 MB
    unsigned short* hb   = (unsigned short*)ws; ws += act_sz;
    unsigned short* sb   = (unsigned short*)ws; ws += act_sz;
    unsigned short* wtq  = (unsigned short*)ws; ws += w_sz;
    unsigned short* wtk  = (unsigned short*)ws; ws += w_sz;
    unsigned short* wtv  = (unsigned short*)ws; ws += w_sz;
    unsigned short* wtq2 = (unsigned short*)ws; ws += w_sz;
    unsigned short* wtk2 = (unsigned short*)ws; ws += w_sz;
    unsigned short* qbuf  = (unsigned short*)ws; ws += act_sz;
    unsigned short* kbuf  = (unsigned short*)ws; ws += act_sz;
    unsigned short* q2buf = (unsigned short*)ws; ws += act_sz;
    unsigned short* k2buf = (unsigned short*)ws; ws += act_sz;
    unsigned short* vtbuf = (unsigned short*)ws; ws += act_sz;

    // 1) convert activations to bf16
    int cvt_blocks = (Mn * Dn / 4) / 256;        // 8192
    cvt_bf16_kernel<<<cvt_blocks, 256, 0, stream>>>(hidden, hb);
    cvt_bf16_kernel<<<cvt_blocks, 256, 0, stream>>>(source, sb);

    // 2) transpose+convert weights
    dim3 tgrid(32, 32), tblk(32, 8);
    transpose_w_kernel<<<tgrid, tblk, 0, stream>>>(Wq,  wtq);
    transpose_w_kernel<<<tgrid, tblk, 0, stream>>>(Wk,  wtk);
    transpose_w_kernel<<<tgrid, tblk, 0, stream>>>(Wv,  wtv);
    transpose_w_kernel<<<tgrid, tblk, 0, stream>>>(Wq2, wtq2);
    transpose_w_kernel<<<tgrid, tblk, 0, stream>>>(Wk2, wtk2);

    // 3) projections
    dim3 ggrid(Dn / 128, Mn / 128);              // (8, 64)
    gemm_proj_kernel<<<ggrid, 256, 0, stream>>>(hb, wtq,  bq,  qbuf,  0);
    gemm_proj_kernel<<<ggrid, 256, 0, stream>>>(hb, wtk,  bk,  kbuf,  0);
    gemm_proj_kernel<<<ggrid, 256, 0, stream>>>(hb, wtq2, bq2, q2buf, 0);
    gemm_proj_kernel<<<ggrid, 256, 0, stream>>>(sb, wtk2, bk2, k2buf, 0);
    gemm_proj_kernel<<<ggrid, 256, 0, stream>>>(hb, wtv,  bv,  vtbuf, 1);

    // 4) attention
    dim3 agrid(Ln / 64, Bn * Hn);                // (16, 128)
    attn_kernel<<<agrid, 256, 0, stream>>>(qbuf, kbuf, q2buf, k2buf, vtbuf, mask, out);
}

// Round 2
// 387.453 us; speedup vs baseline: 1.2644x; 1.2644x over previous
//
#include <hip/hip_runtime.h>
#include <hip/hip_bf16.h>
#include <stdint.h>

#define Bn 8
#define Ln 1024
#define Dn 1024
#define Hn 16
#define HDn 64
#define Mn (Bn*Ln)   // 8192
#define Kn 1024

typedef __attribute__((ext_vector_type(8))) __bf16 bf16x8;
typedef __attribute__((ext_vector_type(4))) float f32x4;

__device__ __forceinline__ unsigned short f2bf(float f) {
    unsigned int u = __float_as_uint(f);
    unsigned int r = (u + 0x7fff + ((u >> 16) & 1)) >> 16;
    return (unsigned short)r;
}

__device__ __forceinline__ void gload_lds16(void* lds, const void* g) {
    __builtin_amdgcn_global_load_lds(
        (const __attribute__((address_space(1))) unsigned int*)g,
        (__attribute__((address_space(3))) unsigned int*)lds,
        16, 0, 0);
}

// ---------------- fp32 -> bf16 convert (hidden + source fused) ----
__global__ void cvt_bf16_kernel(const float* __restrict__ h,
                                const float* __restrict__ s,
                                unsigned short* __restrict__ ho,
                                unsigned short* __restrict__ so) {
    const float* in = blockIdx.y ? s : h;
    unsigned short* out = blockIdx.y ? so : ho;
    size_t i = ((size_t)blockIdx.x * blockDim.x + threadIdx.x) * 4;
    float4 f = *(const float4*)(in + i);
    ushort4 o;
    o.x = f2bf(f.x); o.y = f2bf(f.y); o.z = f2bf(f.z); o.w = f2bf(f.w);
    *(ushort4*)(out + i) = o;
}

// ---------------- W [K][N] fp32 -> W^T [N][K] bf16, 5 weights -----
__global__ void transpose_w_kernel(const float* __restrict__ Wq,
                                   const float* __restrict__ Wk,
                                   const float* __restrict__ Wq2,
                                   const float* __restrict__ Wv,
                                   const float* __restrict__ Wk2,
                                   unsigned short* __restrict__ wcat,
                                   unsigned short* __restrict__ wtv,
                                   unsigned short* __restrict__ wtk2) {
    __shared__ float tile[32][33];
    const float* W; unsigned short* Wt;
    switch (blockIdx.z) {
        case 0: W = Wq;  Wt = wcat;                  break;
        case 1: W = Wk;  Wt = wcat + 1024 * 1024;    break;
        case 2: W = Wq2; Wt = wcat + 2048 * 1024;    break;
        case 3: W = Wv;  Wt = wtv;                   break;
        default:W = Wk2; Wt = wtk2;                  break;
    }
    int bx = blockIdx.x, by = blockIdx.y;
    int tx = threadIdx.x, ty = threadIdx.y;
    int col = bx * 32 + tx;
    for (int i = 0; i < 32; i += 8)
        tile[ty + i][tx] = W[(size_t)(by * 32 + ty + i) * Dn + col];
    __syncthreads();
    int ok = by * 32 + tx;
    for (int i = 0; i < 32; i += 8)
        Wt[(size_t)(bx * 32 + ty + i) * Kn + ok] = f2bf(tile[tx][ty + i]);
}

// ---------------- shared GEMM mainloop (128x128 tile, BK=32) ------
// XOR-swizzled LDS: chunk c of row r stored at slot (c ^ (r&3)).
__device__ __forceinline__ void gemm_mainloop(const unsigned short* __restrict__ A,
                                              const unsigned short* __restrict__ Bt,
                                              unsigned short* As, unsigned short* Bs,
                                              int m0, int n0, f32x4 acc[4][4]) {
    int t = threadIdx.x;
    int lane = t & 63, wave = t >> 6;
    int wm = (wave >> 1) * 64, wn = (wave & 1) * 64;
    int lrow = lane & 15, lquad = lane >> 4;
    int arow = t >> 2;
    int ac = ((t & 3) ^ (arow & 3)) * 8;          // swizzled global chunk
    int rs = lrow & 3;                             // read-side row phase

    for (int k0 = 0; k0 < Kn; k0 += 32) {
        gload_lds16(&As[t * 8],         A  + (size_t)(m0 + arow) * Kn + k0 + ac);
        gload_lds16(&As[(t + 256) * 8], A  + (size_t)(m0 + 64 + arow) * Kn + k0 + ac);
        gload_lds16(&Bs[t * 8],         Bt + (size_t)(n0 + arow) * Kn + k0 + ac);
        gload_lds16(&Bs[(t + 256) * 8], Bt + (size_t)(n0 + 64 + arow) * Kn + k0 + ac);
        __syncthreads();
        bf16x8 af[4], bfr[4];
        for (int i = 0; i < 4; i++)
            af[i] = *(const bf16x8*)&As[(wm + i * 16 + lrow) * 32 + (lquad ^ rs) * 8];
        for (int j = 0; j < 4; j++)
            bfr[j] = *(const bf16x8*)&Bs[(wn + j * 16 + lrow) * 32 + (lquad ^ rs) * 8];
        for (int i = 0; i < 4; i++)
            for (int j = 0; j < 4; j++)
                acc[i][j] = __builtin_amdgcn_mfma_f32_16x16x32_bf16(af[i], bfr[j], acc[i][j], 0, 0, 0);
        __syncthreads();
    }
}

// ---- fused q/k/q2 projections: A=hb [8192,1024], Bt=wcat [3072,1024]
__launch_bounds__(256, 2)
__global__ void gemm_qkq2_kernel(const unsigned short* __restrict__ Abf,
                                 const unsigned short* __restrict__ Bt,
                                 const float* __restrict__ bq,
                                 const float* __restrict__ bk,
                                 const float* __restrict__ bq2,
                                 unsigned short* __restrict__ qbuf,
                                 unsigned short* __restrict__ kbuf,
                                 unsigned short* __restrict__ q2buf) {
    __shared__ __align__(16) unsigned short As[128 * 32];
    __shared__ __align__(16) unsigned short Bs[128 * 32];
    int m0 = blockIdx.y * 128, n0 = blockIdx.x * 128;
    f32x4 acc[4][4] = {};
    gemm_mainloop(Abf, Bt, As, Bs, m0, n0, acc);

    int t = threadIdx.x;
    int lane = t & 63, wave = t >> 6;
    int wm = (wave >> 1) * 64, wn = (wave & 1) * 64;
    int lrow = lane & 15, lquad = lane >> 4;
    for (int j = 0; j < 4; j++) {
        int gn = n0 + wn + j * 16 + lrow;
        int region = gn >> 10, nn = gn & 1023;
        const float* bp = region == 0 ? bq : (region == 1 ? bk : bq2);
        unsigned short* dp = region == 0 ? qbuf : (region == 1 ? kbuf : q2buf);
        float sc = (region == 1) ? 1.0f : 0.125f;   // fold 1/sqrt(HD) into q,q2
        float bv = bp[nn];
        int h = nn >> 6, hd = nn & 63;
        for (int i = 0; i < 4; i++)
            for (int r = 0; r < 4; r++) {
                int gm = m0 + wm + i * 16 + lquad * 4 + r;
                int b = gm >> 10, ll = gm & 1023;
                dp[((size_t)(b * Hn + h) * Ln + ll) * HDn + hd] = f2bf((acc[i][j][r] + bv) * sc);
            }
    }
}

// ---- k2 projection: A=sb, Bt=wtk2, standard [b,h,l,hd] output -----
__launch_bounds__(256, 2)
__global__ void gemm_k2_kernel(const unsigned short* __restrict__ Abf,
                               const unsigned short* __restrict__ Bt,
                               const float* __restrict__ bias,
                               unsigned short* __restrict__ dst) {
    __shared__ __align__(16) unsigned short As[128 * 32];
    __shared__ __align__(16) unsigned short Bs[128 * 32];
    int m0 = blockIdx.y * 128, n0 = blockIdx.x * 128;
    f32x4 acc[4][4] = {};
    gemm_mainloop(Abf, Bt, As, Bs, m0, n0, acc);

    int t = threadIdx.x;
    int lane = t & 63, wave = t >> 6;
    int wm = (wave >> 1) * 64, wn = (wave & 1) * 64;
    int lrow = lane & 15, lquad = lane >> 4;
    for (int j = 0; j < 4; j++) {
        int gn = n0 + wn + j * 16 + lrow;
        float bv = bias[gn];
        int h = gn >> 6, hd = gn & 63;
        for (int i = 0; i < 4; i++)
            for (int r = 0; r < 4; r++) {
                int gm = m0 + wm + i * 16 + lquad * 4 + r;
                int b = gm >> 10, ll = gm & 1023;
                dst[((size_t)(b * Hn + h) * Ln + ll) * HDn + hd] = f2bf(acc[i][j][r] + bv);
            }
    }
}

// ---- V^T projection via swapped operands: C'[chan][token] = (X Wv)^T
__launch_bounds__(256, 2)
__global__ void gemm_vT_kernel(const unsigned short* __restrict__ Wt,   // A: [1024 chan][1024 k]
                               const unsigned short* __restrict__ Xb,   // Bt: [8192 tok][1024 k]
                               const float* __restrict__ bias,
                               unsigned short* __restrict__ vtbuf) {
    __shared__ __align__(16) unsigned short As[128 * 32];
    __shared__ __align__(16) unsigned short Bs[128 * 32];
    int m0 = blockIdx.y * 128;   // channel tile (0..896)
    int n0 = blockIdx.x * 128;   // token tile (0..8064)
    f32x4 acc[4][4] = {};
    gemm_mainloop(Wt, Xb, As, Bs, m0, n0, acc);

    int t = threadIdx.x;
    int lane = t & 63, wave = t >> 6;
    int wm = (wave >> 1) * 64, wn = (wave & 1) * 64;
    int lrow = lane & 15, lquad = lane >> 4;
    for (int j = 0; j < 4; j++) {
        int gn = n0 + wn + j * 16 + lrow;     // token
        int b = gn >> 10, l = gn & 1023;
        for (int i = 0; i < 4; i++)
            for (int r = 0; r < 4; r++) {
                int gm = m0 + wm + i * 16 + lquad * 4 + r;   // channel
                int h = gm >> 6, hd = gm & 63;
                float bv = bias[gm];
                // l-contiguous store -> coalesced
                vtbuf[((size_t)(b * Hn + h) * HDn + hd) * Ln + l] = f2bf(acc[i][j][r] + bv);
            }
    }
}

// ---------------- flash attention over 2 score terms --------------
// LDS tiles XOR-swizzled: 16B chunk c of row r lives at slot (c ^ (r&7)).
__launch_bounds__(256, 4)
__global__ void attn_kernel(const unsigned short* __restrict__ qb,
                            const unsigned short* __restrict__ kb,
                            const unsigned short* __restrict__ q2b,
                            const unsigned short* __restrict__ k2b,
                            const unsigned short* __restrict__ vtb,
                            const float* __restrict__ mask,
                            float* __restrict__ out) {
    __shared__ __align__(16) unsigned short Ks[64 * 64];
    __shared__ __align__(16) unsigned short K2s[64 * 64];
    __shared__ __align__(16) unsigned short VTs[64 * 64];
    __shared__ __align__(16) unsigned short Ps[4 * 16 * 64];

    int bh = blockIdx.x;                 // bh fastest -> same-bh blocks share XCD
    int qt = blockIdx.y;
    int b = bh >> 4;
    int t = threadIdx.x;
    int lane = t & 63, wave = t >> 6;
    int lrow = lane & 15, lquad = lane >> 4;
    int qbase = qt * 64 + wave * 16;

    bf16x8 qf[2], q2f[2];
    for (int kk = 0; kk < 2; kk++) {
        size_t off = ((size_t)bh * Ln + qbase + lrow) * HDn + kk * 32 + lquad * 8;
        qf[kk]  = *(const bf16x8*)(qb + off);
        q2f[kk] = *(const bf16x8*)(q2b + off);
    }

    f32x4 O[4] = {};
    float mrow[4] = {-1e30f, -1e30f, -1e30f, -1e30f};
    float lsum[4] = {};

    int srow = t >> 3;                   // staged row 0..31
    int sc8 = ((t & 7) ^ (srow & 7)) * 8;  // swizzled global chunk offset
    const float* maskb = mask + (size_t)b * Ln;
    int rph = lrow & 7;                  // read-side row phase

    for (int kt = 0; kt < 16; kt++) {
        int key0 = kt * 64;
        gload_lds16(&Ks[t * 8],          kb  + ((size_t)bh * Ln + key0 + srow) * HDn + sc8);
        gload_lds16(&Ks[(t + 256) * 8],  kb  + ((size_t)bh * Ln + key0 + 32 + srow) * HDn + sc8);
        gload_lds16(&K2s[t * 8],         k2b + ((size_t)bh * Ln + key0 + srow) * HDn + sc8);
        gload_lds16(&K2s[(t + 256) * 8], k2b + ((size_t)bh * Ln + key0 + 32 + srow) * HDn + sc8);
        gload_lds16(&VTs[t * 8],         vtb + ((size_t)bh * HDn + srow) * Ln + key0 + sc8);
        gload_lds16(&VTs[(t + 256) * 8], vtb + ((size_t)bh * HDn + 32 + srow) * Ln + key0 + sc8);
        __syncthreads();

        // S init with mask (q,q2 pre-scaled by 0.125 in projection)
        f32x4 S[4];
        for (int j = 0; j < 4; j++) {
            float mk = maskb[key0 + j * 16 + lrow];
            S[j] = (f32x4){mk, mk, mk, mk};
        }
        for (int kk = 0; kk < 2; kk++) {
            for (int j = 0; j < 4; j++) {
                bf16x8 kf = *(const bf16x8*)&Ks[(j * 16 + lrow) * 64 + ((kk * 4 + lquad) ^ rph) * 8];
                S[j] = __builtin_amdgcn_mfma_f32_16x16x32_bf16(qf[kk], kf, S[j], 0, 0, 0);
            }
            for (int j = 0; j < 4; j++) {
                bf16x8 kf = *(const bf16x8*)&K2s[(j * 16 + lrow) * 64 + ((kk * 4 + lquad) ^ rph) * 8];
                S[j] = __builtin_amdgcn_mfma_f32_16x16x32_bf16(q2f[kk], kf, S[j], 0, 0, 0);
            }
        }

        // online softmax (rows on (quad,reg); reduce over lane bits 0..3)
        float newm[4], alpha[4];
        for (int r = 0; r < 4; r++) {
            float mx = fmaxf(fmaxf(S[0][r], S[1][r]), fmaxf(S[2][r], S[3][r]));
            for (int d = 1; d < 16; d <<= 1)
                mx = fmaxf(mx, __shfl_xor(mx, d, 64));
            newm[r] = fmaxf(mrow[r], mx);
            alpha[r] = __expf(mrow[r] - newm[r]);
            mrow[r] = newm[r];
        }
        for (int j = 0; j < 4; j++)
            for (int r = 0; r < 4; r++)
                S[j][r] = __expf(S[j][r] - newm[r]);
        for (int r = 0; r < 4; r++) {
            float s = S[0][r] + S[1][r] + S[2][r] + S[3][r];
            for (int d = 1; d < 16; d <<= 1)
                s += __shfl_xor(s, d, 64);
            lsum[r] = lsum[r] * alpha[r] + s;
        }
        for (int j = 0; j < 4; j++)
            for (int r = 0; r < 4; r++)
                O[j][r] *= alpha[r];

        // P: C-layout -> LDS (wave-private, swizzled) -> A-operand layout
        unsigned short* pw = &Ps[wave * 16 * 64];
        for (int j = 0; j < 4; j++)
            for (int r = 0; r < 4; r++) {
                int pr = lquad * 4 + r;
                int cw = (j * 2 + (lrow >> 3)) ^ (pr & 7);
                pw[pr * 64 + cw * 8 + (lrow & 7)] = f2bf(S[j][r]);
            }
        // no barrier: Ps is wave-private (compiler orders ds_write->ds_read)

        for (int kk = 0; kk < 2; kk++) {
            bf16x8 pf = *(const bf16x8*)&pw[lrow * 64 + ((kk * 4 + lquad) ^ rph) * 8];
            for (int j = 0; j < 4; j++) {
                bf16x8 vf = *(const bf16x8*)&VTs[(j * 16 + lrow) * 64 + ((kk * 4 + lquad) ^ rph) * 8];
                O[j] = __builtin_amdgcn_mfma_f32_16x16x32_bf16(pf, vf, O[j], 0, 0, 0);
            }
        }
        __syncthreads();   // protect K/K2/VT tiles before next staging
    }

    int h = bh & 15;
    for (int r = 0; r < 4; r++) {
        float rl = 1.0f / lsum[r];
        int ql = qbase + lquad * 4 + r;
        for (int j = 0; j < 4; j++)
            out[((size_t)b * Ln + ql) * Dn + h * HDn + j * 16 + lrow] = O[j][r] * rl;
    }
}

extern "C" void kernel_launch(void* const* d_in, const int* in_sizes, int n_in,
                              void* d_out, int out_size, void* d_ws, size_t ws_size,
                              hipStream_t stream) {
    const float* hidden = (const float*)d_in[0];
    const float* mask   = (const float*)d_in[1];
    const float* source = (const float*)d_in[2];
    const float* Wq  = (const float*)d_in[3];
    const float* bq  = (const float*)d_in[4];
    const float* Wk  = (const float*)d_in[5];
    const float* bk  = (const float*)d_in[6];
    const float* Wv  = (const float*)d_in[7];
    const float* bv  = (const float*)d_in[8];
    const float* Wq2 = (const float*)d_in[9];
    const float* bq2 = (const float*)d_in[10];
    const float* Wk2 = (const float*)d_in[11];
    const float* bk2 = (const float*)d_in[12];
    float* out = (float*)d_out;

    char* ws = (char*)d_ws;
    const size_t act_sz = (size_t)Mn * Dn * 2;   // 16 MB
    const size_t w_sz   = (size_t)Kn * Dn * 2;   // 2 MB
    unsigned short* hb    = (unsigned short*)ws; ws += act_sz;
    unsigned short* sb    = (unsigned short*)ws; ws += act_sz;
    unsigned short* wcat  = (unsigned short*)ws; ws += 3 * w_sz;
    unsigned short* wtv   = (unsigned short*)ws; ws += w_sz;
    unsigned short* wtk2  = (unsigned short*)ws; ws += w_sz;
    unsigned short* qbuf  = (unsigned short*)ws; ws += act_sz;
    unsigned short* kbuf  = (unsigned short*)ws; ws += act_sz;
    unsigned short* q2buf = (unsigned short*)ws; ws += act_sz;
    unsigned short* k2buf = (unsigned short*)ws; ws += act_sz;
    unsigned short* vtbuf = (unsigned short*)ws; ws += act_sz;

    // 1) fp32 -> bf16 activations (one dispatch)
    dim3 cgrid((Mn * Dn / 4) / 256, 2);
    cvt_bf16_kernel<<<cgrid, 256, 0, stream>>>(hidden, source, hb, sb);

    // 2) all weight transposes (one dispatch)
    dim3 tgrid(32, 32, 5), tblk(32, 8);
    transpose_w_kernel<<<tgrid, tblk, 0, stream>>>(Wq, Wk, Wq2, Wv, Wk2, wcat, wtv, wtk2);

    // 3) projections
    dim3 g1(3072 / 128, Mn / 128);               // (24, 64)
    gemm_qkq2_kernel<<<g1, 256, 0, stream>>>(hb, wcat, bq, bk, bq2, qbuf, kbuf, q2buf);
    dim3 g2(Dn / 128, Mn / 128);                 // (8, 64)
    gemm_k2_kernel<<<g2, 256, 0, stream>>>(sb, wtk2, bk2, k2buf);
    dim3 g3(Mn / 128, Dn / 128);                 // (64, 8)
    gemm_vT_kernel<<<g3, 256, 0, stream>>>(wtv, hb, bv, vtbuf);

    // 4) attention (bh fastest for XCD/L2 locality)
    dim3 agrid(Bn * Hn, Ln / 64);                // (128, 16)
    attn_kernel<<<agrid, 256, 0, stream>>>(qbuf, kbuf, q2buf, k2buf, vtbuf, mask, out);
}

// Round 3
// 352.276 us; speedup vs baseline: 1.3906x; 1.0999x over previous
//
#include <hip/hip_runtime.h>
#include <hip/hip_bf16.h>
#include <stdint.h>

#define Bn 8
#define Ln 1024
#define Dn 1024
#define Hn 16
#define HDn 64
#define Mn (Bn*Ln)   // 8192
#define Kn 1024

typedef __attribute__((ext_vector_type(8))) __bf16 bf16x8;
typedef __attribute__((ext_vector_type(4))) float f32x4;

__device__ __forceinline__ unsigned short f2bf(float f) {
    unsigned int u = __float_as_uint(f);
    unsigned int r = (u + 0x7fff + ((u >> 16) & 1)) >> 16;
    return (unsigned short)r;
}

__device__ __forceinline__ void gload_lds16(void* lds, const void* g) {
    __builtin_amdgcn_global_load_lds(
        (const __attribute__((address_space(1))) unsigned int*)g,
        (__attribute__((address_space(3))) unsigned int*)lds,
        16, 0, 0);
}

// ---------------- fp32 -> bf16 convert (hidden + source fused) ----
__global__ void cvt_bf16_kernel(const float* __restrict__ h,
                                const float* __restrict__ s,
                                unsigned short* __restrict__ ho,
                                unsigned short* __restrict__ so) {
    const float* in = blockIdx.y ? s : h;
    unsigned short* out = blockIdx.y ? so : ho;
    size_t i = ((size_t)blockIdx.x * blockDim.x + threadIdx.x) * 4;
    float4 f = *(const float4*)(in + i);
    ushort4 o;
    o.x = f2bf(f.x); o.y = f2bf(f.y); o.z = f2bf(f.z); o.w = f2bf(f.w);
    *(ushort4*)(out + i) = o;
}

// ---------------- W [K][N] fp32 -> W^T [N][K] bf16, 5 weights -----
// z=0..3 -> wcat4 regions (Wq,Wk,Wq2,Wk2), z=4 -> wtv
__global__ void transpose_w_kernel(const float* __restrict__ Wq,
                                   const float* __restrict__ Wk,
                                   const float* __restrict__ Wq2,
                                   const float* __restrict__ Wk2,
                                   const float* __restrict__ Wv,
                                   unsigned short* __restrict__ wcat4,
                                   unsigned short* __restrict__ wtv) {
    __shared__ float tile[32][33];
    const float* W; unsigned short* Wt;
    switch (blockIdx.z) {
        case 0: W = Wq;  Wt = wcat4;                 break;
        case 1: W = Wk;  Wt = wcat4 + 1024 * 1024;   break;
        case 2: W = Wq2; Wt = wcat4 + 2048 * 1024;   break;
        case 3: W = Wk2; Wt = wcat4 + 3072 * 1024;   break;
        default:W = Wv;  Wt = wtv;                   break;
    }
    int bx = blockIdx.x, by = blockIdx.y;
    int tx = threadIdx.x, ty = threadIdx.y;
    int col = bx * 32 + tx;
    for (int i = 0; i < 32; i += 8)
        tile[ty + i][tx] = W[(size_t)(by * 32 + ty + i) * Dn + col];
    __syncthreads();
    int ok = by * 32 + tx;
    for (int i = 0; i < 32; i += 8)
        Wt[(size_t)(bx * 32 + ty + i) * Kn + ok] = f2bf(tile[tx][ty + i]);
}

// ---------------- shared GEMM mainloop (128x128 tile, BK=32) ------
// XOR-swizzled LDS: chunk c of row r stored at slot (c ^ (r&3)).
__device__ __forceinline__ void gemm_mainloop(const unsigned short* __restrict__ A,
                                              const unsigned short* __restrict__ Bt,
                                              unsigned short* As, unsigned short* Bs,
                                              int m0, int n0, f32x4 acc[4][4]) {
    int t = threadIdx.x;
    int lane = t & 63, wave = t >> 6;
    int wm = (wave >> 1) * 64, wn = (wave & 1) * 64;
    int lrow = lane & 15, lquad = lane >> 4;
    int arow = t >> 2;
    int ac = ((t & 3) ^ (arow & 3)) * 8;          // swizzled global chunk
    int rs = lrow & 3;                             // read-side row phase

    for (int k0 = 0; k0 < Kn; k0 += 32) {
        gload_lds16(&As[t * 8],         A  + (size_t)(m0 + arow) * Kn + k0 + ac);
        gload_lds16(&As[(t + 256) * 8], A  + (size_t)(m0 + 64 + arow) * Kn + k0 + ac);
        gload_lds16(&Bs[t * 8],         Bt + (size_t)(n0 + arow) * Kn + k0 + ac);
        gload_lds16(&Bs[(t + 256) * 8], Bt + (size_t)(n0 + 64 + arow) * Kn + k0 + ac);
        __syncthreads();
        bf16x8 af[4], bfr[4];
        for (int i = 0; i < 4; i++)
            af[i] = *(const bf16x8*)&As[(wm + i * 16 + lrow) * 32 + (lquad ^ rs) * 8];
        for (int j = 0; j < 4; j++)
            bfr[j] = *(const bf16x8*)&Bs[(wn + j * 16 + lrow) * 32 + (lquad ^ rs) * 8];
        for (int i = 0; i < 4; i++)
            for (int j = 0; j < 4; j++)
                acc[i][j] = __builtin_amdgcn_mfma_f32_16x16x32_bf16(af[i], bfr[j], acc[i][j], 0, 0, 0);
        __syncthreads();
    }
}

// ---- fused q/k/q2/k2 projections: Bt=wcat4 [4096,1024]
// region 0..2: A=hb; region 3: A=sb. q,q2 pre-scaled by 1/sqrt(HD).
__launch_bounds__(256, 2)
__global__ void gemm_qkq2k2_kernel(const unsigned short* __restrict__ hb,
                                   const unsigned short* __restrict__ sb,
                                   const unsigned short* __restrict__ Bt,
                                   const float* __restrict__ bq,
                                   const float* __restrict__ bk,
                                   const float* __restrict__ bq2,
                                   const float* __restrict__ bk2,
                                   unsigned short* __restrict__ qbuf,
                                   unsigned short* __restrict__ kbuf,
                                   unsigned short* __restrict__ q2buf,
                                   unsigned short* __restrict__ k2buf) {
    __shared__ __align__(16) unsigned short As[128 * 32];
    __shared__ __align__(16) unsigned short Bs[128 * 32];
    int m0 = blockIdx.y * 128, n0 = blockIdx.x * 128;
    int region = n0 >> 10;                       // uniform per block
    const unsigned short* A = (region == 3) ? sb : hb;
    f32x4 acc[4][4] = {};
    gemm_mainloop(A, Bt, As, Bs, m0, n0, acc);

    const float* bp = region == 0 ? bq : region == 1 ? bk : region == 2 ? bq2 : bk2;
    unsigned short* dp = region == 0 ? qbuf : region == 1 ? kbuf : region == 2 ? q2buf : k2buf;
    float sc = (region == 0 || region == 2) ? 0.125f : 1.0f;

    int t = threadIdx.x;
    int lane = t & 63, wave = t >> 6;
    int wm = (wave >> 1) * 64, wn = (wave & 1) * 64;
    int lrow = lane & 15, lquad = lane >> 4;
    for (int j = 0; j < 4; j++) {
        int gn = (n0 & 1023) + wn + j * 16 + lrow;
        float bv = bp[gn];
        int h = gn >> 6, hd = gn & 63;
        for (int i = 0; i < 4; i++)
            for (int r = 0; r < 4; r++) {
                int gm = m0 + wm + i * 16 + lquad * 4 + r;
                int b = gm >> 10, ll = gm & 1023;
                dp[((size_t)(b * Hn + h) * Ln + ll) * HDn + hd] = f2bf((acc[i][j][r] + bv) * sc);
            }
    }
}

// ---- V^T projection via swapped operands: C'[chan][token] = (X Wv)^T
__launch_bounds__(256, 2)
__global__ void gemm_vT_kernel(const unsigned short* __restrict__ Wt,   // A: [1024 chan][1024 k]
                               const unsigned short* __restrict__ Xb,   // Bt: [8192 tok][1024 k]
                               const float* __restrict__ bias,
                               unsigned short* __restrict__ vtbuf) {
    __shared__ __align__(16) unsigned short As[128 * 32];
    __shared__ __align__(16) unsigned short Bs[128 * 32];
    int m0 = blockIdx.y * 128;   // channel tile
    int n0 = blockIdx.x * 128;   // token tile
    f32x4 acc[4][4] = {};
    gemm_mainloop(Wt, Xb, As, Bs, m0, n0, acc);

    int t = threadIdx.x;
    int lane = t & 63, wave = t >> 6;
    int wm = (wave >> 1) * 64, wn = (wave & 1) * 64;
    int lrow = lane & 15, lquad = lane >> 4;
    for (int j = 0; j < 4; j++) {
        int gn = n0 + wn + j * 16 + lrow;     // token
        int b = gn >> 10, l = gn & 1023;
        for (int i = 0; i < 4; i++)
            for (int r = 0; r < 4; r++) {
                int gm = m0 + wm + i * 16 + lquad * 4 + r;   // channel
                int h = gm >> 6, hd = gm & 63;
                vtbuf[((size_t)(b * Hn + h) * HDn + hd) * Ln + l] = f2bf(acc[i][j][r] + bias[gm]);
            }
    }
}

// ---------------- flash attention, one-pass (deferred normalization)
// Q-tile 128/block (2 row-tiles/wave). LDS 16B chunks XOR-swizzled by row&7.
__launch_bounds__(256, 3)
__global__ void attn_kernel(const unsigned short* __restrict__ qb,
                            const unsigned short* __restrict__ kb,
                            const unsigned short* __restrict__ q2b,
                            const unsigned short* __restrict__ k2b,
                            const unsigned short* __restrict__ vtb,
                            const float* __restrict__ mask,
                            float* __restrict__ out) {
    __shared__ __align__(16) unsigned short Ks[64 * 64];
    __shared__ __align__(16) unsigned short K2s[64 * 64];
    __shared__ __align__(16) unsigned short VTs[64 * 64];
    __shared__ __align__(16) unsigned short Ps[4 * 32 * 64];

    int bh = blockIdx.x;                 // bh fastest -> same-bh blocks share XCD
    int qt = blockIdx.y;                 // 0..7
    int b = bh >> 4;
    int t = threadIdx.x;
    int lane = t & 63, wave = t >> 6;
    int lrow = lane & 15, lquad = lane >> 4;
    int qbase = qt * 128 + wave * 32;

    // Q/Q2 A-fragments for both 16-row tiles (pre-scaled by 0.125 upstream)
    bf16x8 qf[2][2], q2f[2][2];
    for (int rt = 0; rt < 2; rt++)
        for (int kk = 0; kk < 2; kk++) {
            size_t off = ((size_t)bh * Ln + qbase + rt * 16 + lrow) * HDn + kk * 32 + lquad * 8;
            qf[rt][kk]  = *(const bf16x8*)(qb + off);
            q2f[rt][kk] = *(const bf16x8*)(q2b + off);
        }

    f32x4 O[2][4] = {};
    f32x4 lsum[2] = {};                  // per-lane partial sum of exp, per row-tile/reg

    int srow = t >> 3;
    int sc8 = ((t & 7) ^ (srow & 7)) * 8;
    const float* maskb = mask + (size_t)b * Ln;
    int rph = lrow & 7;
    unsigned short* pw = &Ps[wave * 32 * 64];

    for (int kt = 0; kt < 16; kt++) {
        int key0 = kt * 64;
        gload_lds16(&Ks[t * 8],          kb  + ((size_t)bh * Ln + key0 + srow) * HDn + sc8);
        gload_lds16(&Ks[(t + 256) * 8],  kb  + ((size_t)bh * Ln + key0 + 32 + srow) * HDn + sc8);
        gload_lds16(&K2s[t * 8],         k2b + ((size_t)bh * Ln + key0 + srow) * HDn + sc8);
        gload_lds16(&K2s[(t + 256) * 8], k2b + ((size_t)bh * Ln + key0 + 32 + srow) * HDn + sc8);
        gload_lds16(&VTs[t * 8],         vtb + ((size_t)bh * HDn + srow) * Ln + key0 + sc8);
        gload_lds16(&VTs[(t + 256) * 8], vtb + ((size_t)bh * HDn + 32 + srow) * Ln + key0 + sc8);
        __syncthreads();

        // S init with mask (same key column for both row-tiles)
        f32x4 S[2][4];
        for (int j = 0; j < 4; j++) {
            float mk = maskb[key0 + j * 16 + lrow];
            S[0][j] = (f32x4){mk, mk, mk, mk};
            S[1][j] = S[0][j];
        }
        for (int kk = 0; kk < 2; kk++) {
            for (int j = 0; j < 4; j++) {
                bf16x8 kf = *(const bf16x8*)&Ks[(j * 16 + lrow) * 64 + ((kk * 4 + lquad) ^ rph) * 8];
                S[0][j] = __builtin_amdgcn_mfma_f32_16x16x32_bf16(qf[0][kk], kf, S[0][j], 0, 0, 0);
                S[1][j] = __builtin_amdgcn_mfma_f32_16x16x32_bf16(qf[1][kk], kf, S[1][j], 0, 0, 0);
            }
            for (int j = 0; j < 4; j++) {
                bf16x8 kf = *(const bf16x8*)&K2s[(j * 16 + lrow) * 64 + ((kk * 4 + lquad) ^ rph) * 8];
                S[0][j] = __builtin_amdgcn_mfma_f32_16x16x32_bf16(q2f[0][kk], kf, S[0][j], 0, 0, 0);
                S[1][j] = __builtin_amdgcn_mfma_f32_16x16x32_bf16(q2f[1][kk], kf, S[1][j], 0, 0, 0);
            }
        }

        // one-pass: P = exp(S), accumulate per-lane partial denominators;
        // cross-lane reduction deferred to after the kt loop.
        for (int rt = 0; rt < 2; rt++)
            for (int j = 0; j < 4; j++)
                for (int r = 0; r < 4; r++) {
                    float e = __expf(S[rt][j][r]);
                    lsum[rt][r] += e;
                    int pr = rt * 16 + lquad * 4 + r;
                    int cw = (j * 2 + (lrow >> 3)) ^ (pr & 7);
                    pw[pr * 64 + cw * 8 + (lrow & 7)] = f2bf(e);
                }
        // no barrier: Ps is wave-private (same-wave LDS ordering)

        for (int kk = 0; kk < 2; kk++) {
            bf16x8 pf0 = *(const bf16x8*)&pw[lrow * 64 + ((kk * 4 + lquad) ^ rph) * 8];
            bf16x8 pf1 = *(const bf16x8*)&pw[(16 + lrow) * 64 + ((kk * 4 + lquad) ^ rph) * 8];
            for (int j = 0; j < 4; j++) {
                bf16x8 vf = *(const bf16x8*)&VTs[(j * 16 + lrow) * 64 + ((kk * 4 + lquad) ^ rph) * 8];
                O[0][j] = __builtin_amdgcn_mfma_f32_16x16x32_bf16(pf0, vf, O[0][j], 0, 0, 0);
                O[1][j] = __builtin_amdgcn_mfma_f32_16x16x32_bf16(pf1, vf, O[1][j], 0, 0, 0);
            }
        }
        __syncthreads();   // protect K/K2/VT tiles before next staging
    }

    // final denominator: reduce partials across the 16 lanes of each row group
    for (int rt = 0; rt < 2; rt++)
        for (int r = 0; r < 4; r++) {
            float s = lsum[rt][r];
            for (int d = 1; d < 16; d <<= 1)
                s += __shfl_xor(s, d, 64);
            lsum[rt][r] = s;
        }

    int h = bh & 15;
    for (int rt = 0; rt < 2; rt++)
        for (int r = 0; r < 4; r++) {
            float rl = 1.0f / lsum[rt][r];
            int ql = qbase + rt * 16 + lquad * 4 + r;
            for (int j = 0; j < 4; j++)
                out[((size_t)b * Ln + ql) * Dn + h * HDn + j * 16 + lrow] = O[rt][j][r] * rl;
        }
}

extern "C" void kernel_launch(void* const* d_in, const int* in_sizes, int n_in,
                              void* d_out, int out_size, void* d_ws, size_t ws_size,
                              hipStream_t stream) {
    const float* hidden = (const float*)d_in[0];
    const float* mask   = (const float*)d_in[1];
    const float* source = (const float*)d_in[2];
    const float* Wq  = (const float*)d_in[3];
    const float* bq  = (const float*)d_in[4];
    const float* Wk  = (const float*)d_in[5];
    const float* bk  = (const float*)d_in[6];
    const float* Wv  = (const float*)d_in[7];
    const float* bv  = (const float*)d_in[8];
    const float* Wq2 = (const float*)d_in[9];
    const float* bq2 = (const float*)d_in[10];
    const float* Wk2 = (const float*)d_in[11];
    const float* bk2 = (const float*)d_in[12];
    float* out = (float*)d_out;

    char* ws = (char*)d_ws;
    const size_t act_sz = (size_t)Mn * Dn * 2;   // 16 MB
    const size_t w_sz   = (size_t)Kn * Dn * 2;   // 2 MB
    unsigned short* hb    = (unsigned short*)ws; ws += act_sz;
    unsigned short* sb    = (unsigned short*)ws; ws += act_sz;
    unsigned short* wcat4 = (unsigned short*)ws; ws += 4 * w_sz;
    unsigned short* wtv   = (unsigned short*)ws; ws += w_sz;
    unsigned short* qbuf  = (unsigned short*)ws; ws += act_sz;
    unsigned short* kbuf  = (unsigned short*)ws; ws += act_sz;
    unsigned short* q2buf = (unsigned short*)ws; ws += act_sz;
    unsigned short* k2buf = (unsigned short*)ws; ws += act_sz;
    unsigned short* vtbuf = (unsigned short*)ws; ws += act_sz;

    // 1) fp32 -> bf16 activations
    dim3 cgrid((Mn * Dn / 4) / 256, 2);
    cvt_bf16_kernel<<<cgrid, 256, 0, stream>>>(hidden, source, hb, sb);

    // 2) all weight transposes
    dim3 tgrid(32, 32, 5), tblk(32, 8);
    transpose_w_kernel<<<tgrid, tblk, 0, stream>>>(Wq, Wk, Wq2, Wk2, Wv, wcat4, wtv);

    // 3) projections: fused q/k/q2/k2, then V^T
    dim3 g1(4096 / 128, Mn / 128);               // (32, 64)
    gemm_qkq2k2_kernel<<<g1, 256, 0, stream>>>(hb, sb, wcat4, bq, bk, bq2, bk2,
                                               qbuf, kbuf, q2buf, k2buf);
    dim3 g3(Mn / 128, Dn / 128);                 // (64, 8)
    gemm_vT_kernel<<<g3, 256, 0, stream>>>(wtv, hb, bv, vtbuf);

    // 4) attention (Q-tile 128, one-pass softmax)
    dim3 agrid(Bn * Hn, Ln / 128);               // (128, 8)
    attn_kernel<<<agrid, 256, 0, stream>>>(qbuf, kbuf, q2buf, k2buf, vtbuf, mask, out);
}

// Round 4
// 351.742 us; speedup vs baseline: 1.3928x; 1.0015x over previous
//
#include <hip/hip_runtime.h>
#include <hip/hip_bf16.h>
#include <stdint.h>

#define Bn 8
#define Ln 1024
#define Dn 1024
#define Hn 16
#define HDn 64
#define Mn (Bn*Ln)   // 8192
#define Kn 1024

typedef __attribute__((ext_vector_type(8))) __bf16 bf16x8;
typedef __attribute__((ext_vector_type(4))) float f32x4;

__device__ __forceinline__ unsigned short f2bf(float f) {
    unsigned int u = __float_as_uint(f);
    unsigned int r = (u + 0x7fff + ((u >> 16) & 1)) >> 16;
    return (unsigned short)r;
}

__device__ __forceinline__ void gload_lds16(void* lds, const void* g) {
    __builtin_amdgcn_global_load_lds(
        (const __attribute__((address_space(1))) unsigned int*)g,
        (__attribute__((address_space(3))) unsigned int*)lds,
        16, 0, 0);
}

// ---------------- fp32 -> bf16 convert (hidden + source fused) ----
__global__ void cvt_bf16_kernel(const float* __restrict__ h,
                                const float* __restrict__ s,
                                unsigned short* __restrict__ ho,
                                unsigned short* __restrict__ so) {
    const float* in = blockIdx.y ? s : h;
    unsigned short* out = blockIdx.y ? so : ho;
    size_t i = ((size_t)blockIdx.x * blockDim.x + threadIdx.x) * 4;
    float4 f = *(const float4*)(in + i);
    ushort4 o;
    o.x = f2bf(f.x); o.y = f2bf(f.y); o.z = f2bf(f.z); o.w = f2bf(f.w);
    *(ushort4*)(out + i) = o;
}

// ---------------- W [K][N] fp32 -> W^T [N][K] bf16, 5 weights -----
// z=0..3 -> wcat4 regions (Wq,Wk,Wq2,Wk2), z=4 -> wtv
__global__ void transpose_w_kernel(const float* __restrict__ Wq,
                                   const float* __restrict__ Wk,
                                   const float* __restrict__ Wq2,
                                   const float* __restrict__ Wk2,
                                   const float* __restrict__ Wv,
                                   unsigned short* __restrict__ wcat4,
                                   unsigned short* __restrict__ wtv) {
    __shared__ float tile[32][33];
    const float* W; unsigned short* Wt;
    switch (blockIdx.z) {
        case 0: W = Wq;  Wt = wcat4;                 break;
        case 1: W = Wk;  Wt = wcat4 + 1024 * 1024;   break;
        case 2: W = Wq2; Wt = wcat4 + 2048 * 1024;   break;
        case 3: W = Wk2; Wt = wcat4 + 3072 * 1024;   break;
        default:W = Wv;  Wt = wtv;                   break;
    }
    int bx = blockIdx.x, by = blockIdx.y;
    int tx = threadIdx.x, ty = threadIdx.y;
    int col = bx * 32 + tx;
    for (int i = 0; i < 32; i += 8)
        tile[ty + i][tx] = W[(size_t)(by * 32 + ty + i) * Dn + col];
    __syncthreads();
    int ok = by * 32 + tx;
    for (int i = 0; i < 32; i += 8)
        Wt[(size_t)(bx * 32 + ty + i) * Kn + ok] = f2bf(tile[tx][ty + i]);
}

// ---------------- shared GEMM mainloop (128x128 tile, BK=32) ------
// Paired-row LDS mapping: LDS = 64 phys rows x 128B (8 slots of 16B).
// Thread t stages: p=t>>3, q=t&7, q'=q^(p&7) -> logical m=2p+(q'>>2),
// k-chunk c=q'&3. Fragment read (m,c=lquad): phys row m>>1, slot
// ((m&1)*4+lquad)^((m>>1)&7). All 64 lanes of a ds_read_b128 hit 8
// distinct slots per 128B phase -> conflict-free (vs 8-way before).
__device__ __forceinline__ void gemm_mainloop(const unsigned short* __restrict__ A,
                                              const unsigned short* __restrict__ Bt,
                                              unsigned short* As, unsigned short* Bs,
                                              int m0, int n0, f32x4 acc[4][4]) {
    int t = threadIdx.x;
    int lane = t & 63, wave = t >> 6;
    int wm = (wave >> 1) * 64, wn = (wave & 1) * 64;
    int lrow = lane & 15, lquad = lane >> 4;

    // staging map (constant per thread; only k0 varies)
    int q2 = (t & 7) ^ ((t >> 3) & 7);
    int srow = ((t >> 3) << 1) | (q2 >> 2);      // logical m-row 0..63
    int scol = (q2 & 3) * 8;                     // k-chunk offset
    const unsigned short* ap0 = A  + (size_t)(m0 + srow) * Kn + scol;
    const unsigned short* ap1 = A  + (size_t)(m0 + 64 + srow) * Kn + scol;
    const unsigned short* bp0 = Bt + (size_t)(n0 + srow) * Kn + scol;
    const unsigned short* bp1 = Bt + (size_t)(n0 + 64 + srow) * Kn + scol;

    // read map (per-lane constants)
    int rslot8 = ((((lrow & 1) << 2) | lquad) ^ ((lrow >> 1) & 7)) * 8;
    int rbaseA = ((wm >> 1) + (lrow >> 1)) * 64;
    int rbaseB = ((wn >> 1) + (lrow >> 1)) * 64;

    for (int k0 = 0; k0 < Kn; k0 += 32) {
        gload_lds16(&As[t * 8],         ap0 + k0);
        gload_lds16(&As[(t + 256) * 8], ap1 + k0);
        gload_lds16(&Bs[t * 8],         bp0 + k0);
        gload_lds16(&Bs[(t + 256) * 8], bp1 + k0);
        __syncthreads();
        bf16x8 af[4], bfr[4];
        for (int i = 0; i < 4; i++)
            af[i] = *(const bf16x8*)&As[rbaseA + i * 8 * 64 + rslot8];
        for (int j = 0; j < 4; j++)
            bfr[j] = *(const bf16x8*)&Bs[rbaseB + j * 8 * 64 + rslot8];
        for (int i = 0; i < 4; i++)
            for (int j = 0; j < 4; j++)
                acc[i][j] = __builtin_amdgcn_mfma_f32_16x16x32_bf16(af[i], bfr[j], acc[i][j], 0, 0, 0);
        __syncthreads();
    }
}

// ---- all 5 projections in ONE dispatch (2560 linearized blocks) ----
// blocks 0..2047:   q/k/q2/k2 (Bt=wcat4 [4096,1024]; region 3 uses sb)
// blocks 2048..2559: V^T via swapped operands (A=wtv, Bt=hb)
__launch_bounds__(256, 2)
__global__ void gemm_all_kernel(const unsigned short* __restrict__ hb,
                                const unsigned short* __restrict__ sb,
                                const unsigned short* __restrict__ wcat4,
                                const unsigned short* __restrict__ wtv,
                                const float* __restrict__ bq,
                                const float* __restrict__ bk,
                                const float* __restrict__ bq2,
                                const float* __restrict__ bk2,
                                const float* __restrict__ bv,
                                unsigned short* __restrict__ qbuf,
                                unsigned short* __restrict__ kbuf,
                                unsigned short* __restrict__ q2buf,
                                unsigned short* __restrict__ k2buf,
                                unsigned short* __restrict__ vtbuf) {
    __shared__ __align__(16) unsigned short As[128 * 32];
    __shared__ __align__(16) unsigned short Bs[128 * 32];
    int bid = blockIdx.x;
    int t = threadIdx.x;
    int lane = t & 63, wave = t >> 6;
    int wm = (wave >> 1) * 64, wn = (wave & 1) * 64;
    int lrow = lane & 15, lquad = lane >> 4;
    f32x4 acc[4][4] = {};

    if (bid < 2048) {
        int n0 = (bid & 31) * 128, m0 = (bid >> 5) * 128;
        int region = n0 >> 10;
        const unsigned short* A = (region == 3) ? sb : hb;
        gemm_mainloop(A, wcat4, As, Bs, m0, n0, acc);

        const float* bp = region == 0 ? bq : region == 1 ? bk : region == 2 ? bq2 : bk2;
        unsigned short* dp = region == 0 ? qbuf : region == 1 ? kbuf : region == 2 ? q2buf : k2buf;
        float sc = (region == 0 || region == 2) ? 0.125f : 1.0f;
        for (int j = 0; j < 4; j++) {
            int gn = (n0 & 1023) + wn + j * 16 + lrow;
            float bv_ = bp[gn];
            int h = gn >> 6, hd = gn & 63;
            for (int i = 0; i < 4; i++)
                for (int r = 0; r < 4; r++) {
                    int gm = m0 + wm + i * 16 + lquad * 4 + r;
                    int b = gm >> 10, ll = gm & 1023;
                    dp[((size_t)(b * Hn + h) * Ln + ll) * HDn + hd] = f2bf((acc[i][j][r] + bv_) * sc);
                }
        }
    } else {
        int b2 = bid - 2048;
        int n0 = (b2 & 63) * 128;     // token tile
        int m0 = (b2 >> 6) * 128;     // channel tile
        gemm_mainloop(wtv, hb, As, Bs, m0, n0, acc);

        for (int j = 0; j < 4; j++) {
            int gn = n0 + wn + j * 16 + lrow;     // token
            int b = gn >> 10, l = gn & 1023;
            for (int i = 0; i < 4; i++)
                for (int r = 0; r < 4; r++) {
                    int gm = m0 + wm + i * 16 + lquad * 4 + r;   // channel
                    int h = gm >> 6, hd = gm & 63;
                    vtbuf[((size_t)(b * Hn + h) * HDn + hd) * Ln + l] = f2bf(acc[i][j][r] + bv[gm]);
                }
        }
    }
}

// ---------------- flash attention, one-pass (deferred normalization)
// Q-tile 128/block (2 row-tiles/wave). LDS 16B chunks XOR-swizzled by row&7.
__launch_bounds__(256, 3)
__global__ void attn_kernel(const unsigned short* __restrict__ qb,
                            const unsigned short* __restrict__ kb,
                            const unsigned short* __restrict__ q2b,
                            const unsigned short* __restrict__ k2b,
                            const unsigned short* __restrict__ vtb,
                            const float* __restrict__ mask,
                            float* __restrict__ out) {
    __shared__ __align__(16) unsigned short Ks[64 * 64];
    __shared__ __align__(16) unsigned short K2s[64 * 64];
    __shared__ __align__(16) unsigned short VTs[64 * 64];
    __shared__ __align__(16) unsigned short Ps[4 * 32 * 64];

    int bh = blockIdx.x;                 // bh fastest -> same-bh blocks share XCD
    int qt = blockIdx.y;                 // 0..7
    int b = bh >> 4;
    int t = threadIdx.x;
    int lane = t & 63, wave = t >> 6;
    int lrow = lane & 15, lquad = lane >> 4;
    int qbase = qt * 128 + wave * 32;

    bf16x8 qf[2][2], q2f[2][2];
    for (int rt = 0; rt < 2; rt++)
        for (int kk = 0; kk < 2; kk++) {
            size_t off = ((size_t)bh * Ln + qbase + rt * 16 + lrow) * HDn + kk * 32 + lquad * 8;
            qf[rt][kk]  = *(const bf16x8*)(qb + off);
            q2f[rt][kk] = *(const bf16x8*)(q2b + off);
        }

    f32x4 O[2][4] = {};
    f32x4 lsum[2] = {};

    int srow = t >> 3;
    int sc8 = ((t & 7) ^ (srow & 7)) * 8;
    const float* maskb = mask + (size_t)b * Ln;
    int rph = lrow & 7;
    unsigned short* pw = &Ps[wave * 32 * 64];

    for (int kt = 0; kt < 16; kt++) {
        int key0 = kt * 64;
        gload_lds16(&Ks[t * 8],          kb  + ((size_t)bh * Ln + key0 + srow) * HDn + sc8);
        gload_lds16(&Ks[(t + 256) * 8],  kb  + ((size_t)bh * Ln + key0 + 32 + srow) * HDn + sc8);
        gload_lds16(&K2s[t * 8],         k2b + ((size_t)bh * Ln + key0 + srow) * HDn + sc8);
        gload_lds16(&K2s[(t + 256) * 8], k2b + ((size_t)bh * Ln + key0 + 32 + srow) * HDn + sc8);
        gload_lds16(&VTs[t * 8],         vtb + ((size_t)bh * HDn + srow) * Ln + key0 + sc8);
        gload_lds16(&VTs[(t + 256) * 8], vtb + ((size_t)bh * HDn + 32 + srow) * Ln + key0 + sc8);
        __syncthreads();

        f32x4 S[2][4];
        for (int j = 0; j < 4; j++) {
            float mk = maskb[key0 + j * 16 + lrow];
            S[0][j] = (f32x4){mk, mk, mk, mk};
            S[1][j] = S[0][j];
        }
        for (int kk = 0; kk < 2; kk++) {
            for (int j = 0; j < 4; j++) {
                bf16x8 kf = *(const bf16x8*)&Ks[(j * 16 + lrow) * 64 + ((kk * 4 + lquad) ^ rph) * 8];
                S[0][j] = __builtin_amdgcn_mfma_f32_16x16x32_bf16(qf[0][kk], kf, S[0][j], 0, 0, 0);
                S[1][j] = __builtin_amdgcn_mfma_f32_16x16x32_bf16(qf[1][kk], kf, S[1][j], 0, 0, 0);
            }
            for (int j = 0; j < 4; j++) {
                bf16x8 kf = *(const bf16x8*)&K2s[(j * 16 + lrow) * 64 + ((kk * 4 + lquad) ^ rph) * 8];
                S[0][j] = __builtin_amdgcn_mfma_f32_16x16x32_bf16(q2f[0][kk], kf, S[0][j], 0, 0, 0);
                S[1][j] = __builtin_amdgcn_mfma_f32_16x16x32_bf16(q2f[1][kk], kf, S[1][j], 0, 0, 0);
            }
        }

        for (int rt = 0; rt < 2; rt++)
            for (int j = 0; j < 4; j++)
                for (int r = 0; r < 4; r++) {
                    float e = __expf(S[rt][j][r]);
                    lsum[rt][r] += e;
                    int pr = rt * 16 + lquad * 4 + r;
                    int cw = (j * 2 + (lrow >> 3)) ^ (pr & 7);
                    pw[pr * 64 + cw * 8 + (lrow & 7)] = f2bf(e);
                }

        for (int kk = 0; kk < 2; kk++) {
            bf16x8 pf0 = *(const bf16x8*)&pw[lrow * 64 + ((kk * 4 + lquad) ^ rph) * 8];
            bf16x8 pf1 = *(const bf16x8*)&pw[(16 + lrow) * 64 + ((kk * 4 + lquad) ^ rph) * 8];
            for (int j = 0; j < 4; j++) {
                bf16x8 vf = *(const bf16x8*)&VTs[(j * 16 + lrow) * 64 + ((kk * 4 + lquad) ^ rph) * 8];
                O[0][j] = __builtin_amdgcn_mfma_f32_16x16x32_bf16(pf0, vf, O[0][j], 0, 0, 0);
                O[1][j] = __builtin_amdgcn_mfma_f32_16x16x32_bf16(pf1, vf, O[1][j], 0, 0, 0);
            }
        }
        __syncthreads();
    }

    for (int rt = 0; rt < 2; rt++)
        for (int r = 0; r < 4; r++) {
            float s = lsum[rt][r];
            for (int d = 1; d < 16; d <<= 1)
                s += __shfl_xor(s, d, 64);
            lsum[rt][r] = s;
        }

    int h = bh & 15;
    for (int rt = 0; rt < 2; rt++)
        for (int r = 0; r < 4; r++) {
            float rl = 1.0f / lsum[rt][r];
            int ql = qbase + rt * 16 + lquad * 4 + r;
            for (int j = 0; j < 4; j++)
                out[((size_t)b * Ln + ql) * Dn + h * HDn + j * 16 + lrow] = O[rt][j][r] * rl;
        }
}

extern "C" void kernel_launch(void* const* d_in, const int* in_sizes, int n_in,
                              void* d_out, int out_size, void* d_ws, size_t ws_size,
                              hipStream_t stream) {
    const float* hidden = (const float*)d_in[0];
    const float* mask   = (const float*)d_in[1];
    const float* source = (const float*)d_in[2];
    const float* Wq  = (const float*)d_in[3];
    const float* bq  = (const float*)d_in[4];
    const float* Wk  = (const float*)d_in[5];
    const float* bk  = (const float*)d_in[6];
    const float* Wv  = (const float*)d_in[7];
    const float* bv  = (const float*)d_in[8];
    const float* Wq2 = (const float*)d_in[9];
    const float* bq2 = (const float*)d_in[10];
    const float* Wk2 = (const float*)d_in[11];
    const float* bk2 = (const float*)d_in[12];
    float* out = (float*)d_out;

    char* ws = (char*)d_ws;
    const size_t act_sz = (size_t)Mn * Dn * 2;   // 16 MB
    const size_t w_sz   = (size_t)Kn * Dn * 2;   // 2 MB
    unsigned short* hb    = (unsigned short*)ws; ws += act_sz;
    unsigned short* sb    = (unsigned short*)ws; ws += act_sz;
    unsigned short* wcat4 = (unsigned short*)ws; ws += 4 * w_sz;
    unsigned short* wtv   = (unsigned short*)ws; ws += w_sz;
    unsigned short* qbuf  = (unsigned short*)ws; ws += act_sz;
    unsigned short* kbuf  = (unsigned short*)ws; ws += act_sz;
    unsigned short* q2buf = (unsigned short*)ws; ws += act_sz;
    unsigned short* k2buf = (unsigned short*)ws; ws += act_sz;
    unsigned short* vtbuf = (unsigned short*)ws; ws += act_sz;

    // 1) fp32 -> bf16 activations
    dim3 cgrid((Mn * Dn / 4) / 256, 2);
    cvt_bf16_kernel<<<cgrid, 256, 0, stream>>>(hidden, source, hb, sb);

    // 2) all weight transposes
    dim3 tgrid(32, 32, 5), tblk(32, 8);
    transpose_w_kernel<<<tgrid, tblk, 0, stream>>>(Wq, Wk, Wq2, Wk2, Wv, wcat4, wtv);

    // 3) all 5 projections, one dispatch
    gemm_all_kernel<<<2560, 256, 0, stream>>>(hb, sb, wcat4, wtv,
                                              bq, bk, bq2, bk2, bv,
                                              qbuf, kbuf, q2buf, k2buf, vtbuf);

    // 4) attention (Q-tile 128, one-pass softmax)
    dim3 agrid(Bn * Hn, Ln / 128);               // (128, 8)
    attn_kernel<<<agrid, 256, 0, stream>>>(qbuf, kbuf, q2buf, k2buf, vtbuf, mask, out);
}